// Round 4
// baseline (223.788 us; speedup 1.0000x reference)
//
#include <hip/hip_runtime.h>

// NMS3D (4,4,32,256,256) fp32, strict 26-neighbor max.
// R10: R9 shape (independent blocks, stage -> one sync -> compute), tiles
// shrunk again for occupancy/turnover.
// R9 post-mortem: 62us kernel slice at ~3.6 TB/s effective — latency-bound,
// not BW-bound (per-pipe arithmetic: VALU 6.5us, LDS 15us, HBM ~36us floor).
// 4 blocks/CU left stage-drain partially exposed. R10: KD=2, HC=4 ->
// 4 planes x 6 rows = 24 KiB LDS -> 6 blocks/CU (24 waves), 16384 blocks,
// 64 sequenced/CU. Read amp 3.0x (402 MB) is L2/L3-served (R8 FETCH=89MB
// proved input is cache-resident) — L2 has ~3x headroom at this rate.
// Staging is uniform: wave wv DMAs exactly plane j=wv (6 rows, 6 DMA instrs).
// Staging stays fire-and-forget global_load_lds DMA (R1-R5: register
// pipelines get de-pipelined). Math verified (absmax 0.0 R6-R9).

typedef float v4f __attribute__((ext_vector_type(4)));

constexpr int W  = 256;
constexpr int H  = 256;
constexpr int D  = 32;
constexpr int SH = W;
constexpr int SD = W * H;
constexpr int KD = 2;                  // d outputs per block
constexpr int HC = 4;                  // h rows per block
constexpr int BC = 16;                 // B*CH
constexpr int DG = D / KD;             // 16
constexpr int HG = H / HC;             // 64
constexpr int NPL = KD + 2;            // 4 staged planes
constexpr int NR  = HC + 2;            // 6 staged rows per plane
constexpr int TROWS = NPL * NR;        // 24 rows of W floats = 24 KiB

__device__ __forceinline__ v4f vmax4(v4f a, v4f b) {
    return (v4f){fmaxf(a.x, b.x), fmaxf(a.y, b.y), fmaxf(a.z, b.z), fmaxf(a.w, b.w)};
}

// One output row from its 9 staged rows (3 h-rows x 3 planes). Verified math
// (absmax 0.0 in R6-R9): separable vertical max, lane shuffles for w-edges.
__device__ __forceinline__ v4f nms_row(v4f m0, v4f m1, v4f m2,
                                       v4f c0, v4f c1, v4f c2,
                                       v4f p0, v4f p1, v4f p2,
                                       bool valid, int lane) {
    const v4f a3m = vmax4(vmax4(m0, m1), m2);   // plane d-1, all 3 rows
    const v4f a3p = vmax4(vmax4(p0, p1), p2);   // plane d+1, all 3 rows
    const v4f a20 = vmax4(c0, c2);              // plane d, h +- 1
    const v4f v8  = vmax4(vmax4(a3m, a3p), a20);
    const v4f c   = c1;

    const float l8 = __shfl_up(v8.w, 1);     // lane0 garbage, masked below
    const float r8 = __shfl_down(v8.x, 1);   // lane63 garbage, masked below
    const float lc = __shfl_up(c.w, 1);
    const float rc = __shfl_down(c.x, 1);

    float n0 = fmaxf(fmaxf(l8,   v8.x), v8.y);
    float n1 = fmaxf(fmaxf(v8.x, v8.y), v8.z);
    float n2 = fmaxf(fmaxf(v8.y, v8.z), v8.w);
    float n3 = fmaxf(fmaxf(v8.z, v8.w), r8);
    n0 = fmaxf(n0, fmaxf(lc,  c.y));
    n1 = fmaxf(n1, fmaxf(c.x, c.z));
    n2 = fmaxf(n2, fmaxf(c.y, c.w));
    n3 = fmaxf(n3, fmaxf(c.z, rc));

    v4f o;
    o.x = (valid && lane > 0  && c.x > n0) ? c.x : 0.f;
    o.y = (valid && c.y > n1) ? c.y : 0.f;
    o.z = (valid && c.z > n2) ? c.z : 0.f;
    o.w = (valid && lane < 63 && c.w > n3) ? c.w : 0.f;
    return o;
}

__global__ __launch_bounds__(256, 6) void nms3d_kernel(const float* __restrict__ x,
                                                       float* __restrict__ out) {
    __shared__ float lds[TROWS * W];   // 24 KiB -> 6 blocks/CU

    const int blk  = blockIdx.x;
    const int wv   = threadIdx.x >> 6;   // 0..3
    const int lane = threadIdx.x & 63;
    const int hc   = blk & (HG - 1);            // fastest: h-neighbors share halo in L2
    const int dg   = (blk >> 6) & (DG - 1);
    const int bc   = blk >> 10;
    const int d0   = dg * KD;
    const int h0   = hc * HC;

    const float* vol = x + bc * (D * SD);

    // ---- stage: wave wv stages plane j=wv (6 rows, 6 DMA instrs) ----
    {
        int p = d0 - 1 + wv;  p = p < 0 ? 0 : (p > D - 1 ? D - 1 : p);
        const float* src = vol + p * SD + (lane << 2);
        float* dst = &lds[(wv * NR) * W];
        #pragma unroll
        for (int r = 0; r < NR; ++r) {
            int hh = h0 - 1 + r; hh = hh < 0 ? 0 : (hh > H - 1 ? H - 1 : hh);
            // lane i's 16B land at rowbase + 16*i -> exact row-major row (DMA constraint)
            __builtin_amdgcn_global_load_lds(
                (const __attribute__((address_space(1))) unsigned int*)(src + hh * SH),
                (__attribute__((address_space(3))) unsigned int*)(dst + r * W),
                16, 0, 0);
        }
    }
    __syncthreads();   // drains vmcnt (DMA) then barrier — the block's only sync

    // ---- compute: wave wv -> plane d0 + (wv>>1), rows r0 = (wv&1)*2 .. +1 ----
    const int pi = wv >> 1;              // 0..1: output plane within block
    const int r0 = (wv & 1) * 2;         // 0 or 2: first output row within block
    const int d  = d0 + pi;
    const bool dv = (d > 0) && (d < D - 1);
    const int h  = h0 + r0;
    const bool hv0 = (h > 0) && (h < H - 1);      // wave-uniform
    const bool hv1 = (h + 1 < H - 1);             // h+1 >= 1 always

    const float* Lm = lds + (pi * NR + r0) * W + (lane << 2);  // plane d-1, staged row r0
    const float* L0 = Lm + NR * W;                             // plane d
    const float* Lp = L0 + NR * W;                             // plane d+1

    // staged rows r0..r0+3 of each plane feed output rows r0, r0+1
    const v4f m0 = *(const v4f*)(Lm + 0 * W), m1 = *(const v4f*)(Lm + 1 * W);
    const v4f m2 = *(const v4f*)(Lm + 2 * W), m3 = *(const v4f*)(Lm + 3 * W);
    const v4f c0 = *(const v4f*)(L0 + 0 * W), c1 = *(const v4f*)(L0 + 1 * W);
    const v4f c2 = *(const v4f*)(L0 + 2 * W), c3 = *(const v4f*)(L0 + 3 * W);
    const v4f p0 = *(const v4f*)(Lp + 0 * W), p1 = *(const v4f*)(Lp + 1 * W);
    const v4f p2 = *(const v4f*)(Lp + 2 * W), p3 = *(const v4f*)(Lp + 3 * W);

    float* orow = out + bc * (D * SD) + d * SD + h * SH + (lane << 2);
    const v4f o0 = nms_row(m0, m1, m2, c0, c1, c2, p0, p1, p2, hv0 && dv, lane);
    __builtin_nontemporal_store(o0, (v4f*)orow);
    const v4f o1 = nms_row(m1, m2, m3, c1, c2, c3, p1, p2, p3, hv1 && dv, lane);
    __builtin_nontemporal_store(o1, (v4f*)(orow + SH));
}

extern "C" void kernel_launch(void* const* d_in, const int* in_sizes, int n_in,
                              void* d_out, int out_size, void* d_ws, size_t ws_size,
                              hipStream_t stream) {
    const float* x = (const float*)d_in[0];
    float* out = (float*)d_out;
    // blocks = BC * DG * HG = 16*16*64 = 16384, 256 threads each, 6 blocks/CU
    const int grid = BC * DG * HG;
    nms3d_kernel<<<grid, 256, 0, stream>>>(x, out);
}